// Round 7
// baseline (144.339 us; speedup 1.0000x reference)
//
#include <hip/hip_runtime.h>
#include <math.h>

// Problem constants (B,N,C fixed by the reference setup).
#define BB 16
#define NN 2048
#define CC 64
#define TPB 256
#define MROWS 8           // rows per block-tile, shared by all 4 waves (split-K)
#define E_CONST 2.71828182845904523536f

// ---------------------------------------------------------------------------
// K_pre: zero the A accumulator (d_out) everywhere; blocks 0..BB-1 also run
// ballot-based kept/pruned compaction for batch b and zero S[b,:].
// ---------------------------------------------------------------------------
__global__ __launch_bounds__(TPB) void k_pre(const float* __restrict__ keep,
                                             float* __restrict__ outz,
                                             float* __restrict__ S,
                                             int* __restrict__ cntP,
                                             int* __restrict__ cntK,
                                             int* __restrict__ listP,
                                             int* __restrict__ listK) {
    const int tid = threadIdx.x, lane = tid & 63;

    float4* o4 = (float4*)outz + (size_t)blockIdx.x * 1024;
    float4 z = {0.0f, 0.0f, 0.0f, 0.0f};
#pragma unroll
    for (int i = 0; i < 4; ++i) o4[i * TPB + tid] = z;

    const int b = blockIdx.x;
    if (b >= BB) return;

    __shared__ int cP, cK;
    if (tid == 0) { cP = 0; cK = 0; }
    __syncthreads();
    for (int i = tid; i < NN; i += TPB) S[b * NN + i] = 0.0f;
    const unsigned long long lt = (lane == 63) ? 0x7fffffffffffffffull
                                               : ((1ull << lane) - 1ull);
#pragma unroll
    for (int it = 0; it < NN / TPB; ++it) {
        int n = it * TPB + tid;
        bool kp = keep[b * NN + n] != 0.0f;
        unsigned long long mk = __ballot(kp);
        int nk = __popcll(mk);
        int bk = 0, bp = 0;
        if (lane == 0) {
            bk = atomicAdd(&cK, nk);
            bp = atomicAdd(&cP, 64 - nk);
        }
        bk = __shfl(bk, 0); bp = __shfl(bp, 0);
        int pk = __popcll(mk & lt);
        if (kp) listK[b * NN + bk + pk] = n;
        else    listP[b * NN + bp + (lane - pk)] = n;
    }
    __syncthreads();
    if (tid == 0) { cntP[b] = cP; cntK[b] = cK; }
}

// ---------------------------------------------------------------------------
// K_pre2 (R1-verified): ONE WAVE PER KEPT TOKEN.
//  - wave loads x[tok*64+lane] (coalesced 256B), norm via 6x shfl_xor,
//    transposed scatter store into colM. b = id&15 -> XCD pinning.
//  - zero-fills [K, K+128): tiler never reads past colp = K+127.
// ---------------------------------------------------------------------------
__global__ __launch_bounds__(TPB) void k_pre2(const float* __restrict__ x,
                                              const int* __restrict__ cntK,
                                              const int* __restrict__ listK,
                                              float* __restrict__ colMf) {
    const int b    = blockIdx.x & 15;
    const int seg  = blockIdx.x >> 4;          // 0..63
    const int lane = threadIdx.x & 63;
    const int wid  = threadIdx.x >> 6;
    const int wave = seg * 4 + wid;            // 0..255 per batch
    const int K    = cntK[b];
    const int Kend = min(NN, K + 128);

    const float* xb = x + (size_t)b * NN * CC;
    float* cf = colMf + (size_t)b * 16 * NN * 4;   // batch's [16][NN] float4

    for (int colp = wave; colp < Kend; colp += 256) {
        float v = 0.0f;
        if (colp < K) {
            int tok = listK[b * NN + colp];
            float xv = xb[(size_t)tok * CC + lane];
            float sq = xv * xv;
#pragma unroll
            for (int off = 32; off; off >>= 1) sq += __shfl_xor(sq, off, 64);
            v = xv / (sqrtf(sq) + 1e-6f);
        }
        // float4 element (k4 = lane>>2, colp), component lane&3
        cf[((size_t)(lane >> 2) * NN + colp) * 4 + (lane & 3)] = v;
    }
}

// ---------------------------------------------------------------------------
// K3: GEMM-argmax. R22: PERSISTENT BLOCKS -- kill the dead-block dilution.
// R6 post-mortem: split-K structure is right (64.9us, VGPR 40), but grid
// 4096 has ~2048 blocks exiting at `base >= P`; CU workgroup slots fill
// with a ~50/50 live/dead mix -> time-avg live waves/CU ~13 of 32 (the
// measured 40% occupancy). VALU floor ~16us + L1/L2 floor ~15us need more
// co-resident live waves to overlap.
// Fix: launch exactly 2048 blocks; block B keeps b = B&15 (batch/XCD pin:
// 2048 % 16 == 0) and walks slots {B>>4, B>>4+128}. For P~1024 that is ~1
// active tile per block -> every resident block is live.
//  - tile body BYTE-IDENTICAL to R6 (same k4-ascending/xyzw FMA chains,
//    same split-K cols, same merge+emission; identical numerics).
//  - one extra __syncthreads() at iteration end protects the 128B mW merge
//    table (WAR across slots); trip count block-uniform -> barrier-safe.
//  - NO min-waves launch_bounds (R2: capped VGPR 32, serialized streams).
// Falsifier ladder: occ flat -> slot-dilution theory wrong; occ up dur flat
// -> L1/L2-service wall -> next: MROWS 16 persistent (halves traffic).
// ---------------------------------------------------------------------------
template <int J>
__device__ __forceinline__ void tile_body(const float4* __restrict__ x4,
                                          const float4* __restrict__ cm,
                                          const int* rtok, int cstart, int K,
                                          int lane, float* tmax,
                                          unsigned long long* msk) {
    float acc[MROWS][J];
#pragma unroll
    for (int r = 0; r < MROWS; ++r)
#pragma unroll
        for (int j = 0; j < J; ++j) acc[r][j] = 0.0f;

#pragma unroll 2
    for (int k4 = 0; k4 < 16; ++k4) {
        float4 rv[MROWS];
#pragma unroll
        for (int r = 0; r < MROWS; ++r)         // wave-uniform -> s_load
            rv[r] = x4[(size_t)rtok[r] * 16 + k4];
        const float4* cmk = cm + (size_t)k4 * NN + cstart + lane;
        float4 cv[J];
#pragma unroll
        for (int j = 0; j < J; ++j)             // coalesced b128 streams
            cv[j] = cmk[j * 64];
#pragma unroll
        for (int r = 0; r < MROWS; ++r)
#pragma unroll
            for (int j = 0; j < J; ++j)
                acc[r][j] = fmaf(rv[r].x, cv[j].x,
                            fmaf(rv[r].y, cv[j].y,
                            fmaf(rv[r].z, cv[j].z,
                            fmaf(rv[r].w, cv[j].w, acc[r][j]))));
    }

    const int cb0 = cstart >> 6;
#pragma unroll
    for (int r = 0; r < MROWS; ++r)
#pragma unroll
        for (int j = 0; j < J; ++j) {
            int colp = cstart + j * 64 + lane;
            float s = (colp < K) ? acc[r][j] : -1.0e30f;
            unsigned long long bit = 1ull << (cb0 + j);
            if (s > tmax[r])       { tmax[r] = s; msk[r] = bit; }
            else if (s == tmax[r])  msk[r] |= bit;
        }
}

__global__ __launch_bounds__(TPB) void k_argmax(
    const float* __restrict__ x,      // [B,N,C]
    const float4* __restrict__ colM,  // [B,16,N] float4
    const int*   __restrict__ cntP,
    const int*   __restrict__ cntK,
    const int*   __restrict__ listP,
    const int*   __restrict__ listK,
    float* __restrict__ S,            // [B,N]   zeroed by k_pre
    float* __restrict__ A) {          // [B,N,C] zeroed by k_pre; aliases d_out

    const int b = blockIdx.x & 15;
    const int P = cntP[b], K = cntK[b];

    const int tid = threadIdx.x;
    const int wid = tid >> 6;
    const int lane = tid & 63;

    const float4* x4 = (const float4*)(x + (size_t)b * NN * CC);
    const float4* cm = colM + (size_t)b * 16 * NN;
    const int NT = (K + 127) >> 7;

    __shared__ float mW[MROWS][4];

    // Persistent slot walk: slots {B>>4, B>>4+128} of batch b (ascending).
    for (int slot = blockIdx.x >> 4; slot < NN / MROWS; slot += 128) {
        const int base = slot * MROWS;
        if (base >= P) break;                  // block-uniform -> safe

        int rtok[MROWS];
#pragma unroll
        for (int r = 0; r < MROWS; ++r) {
            int rid = base + r;
            int tok = (rid < P) ? listP[b * NN + rid] : 0;
            rtok[r] = __builtin_amdgcn_readfirstlane(tok);
        }

        float              tmax[MROWS];
        unsigned long long msk[MROWS];
#pragma unroll
        for (int r = 0; r < MROWS; ++r) { tmax[r] = -3.0e38f; msk[r] = 0ull; }

        // Split-K: wave wid owns 128-col tiles t = wid, wid+4, ...
        for (int t = wid; t < NT; t += 4)
            tile_body<2>(x4, cm, rtok, t << 7, K, lane, tmax, msk);

        // ---- merge per-wave maxima across the block (128B LDS) ----
        const int nvr = min(MROWS, P - base);
#pragma unroll
        for (int r = 0; r < MROWS; ++r) {
            float m = tmax[r];
#pragma unroll
            for (int off = 32; off; off >>= 1)
                m = fmaxf(m, __shfl_xor(m, off, 64));
            if (lane == 0) mW[r][wid] = m;
        }
        __syncthreads();

        // ---- edge emission: each wave emits its disjoint col subset ----
        for (int r = 0; r < nvr; ++r) {
            float M = fmaxf(fmaxf(mW[r][0], mW[r][1]),
                            fmaxf(mW[r][2], mW[r][3]));
            unsigned long long bal = __ballot(tmax[r] == M && msk[r] != 0ull);
            if (bal == 0ull) continue;        // this wave holds no winners
            int src = rtok[r];
            float xv = x[(size_t)(b * NN + src) * CC + lane];
            float sq = xv * xv;
#pragma unroll
            for (int off = 32; off; off >>= 1) sq += __shfl_xor(sq, off, 64);
            float ivr = 1.0f / (sqrtf(sq) + 1e-6f);
            float wgt = expf(M * ivr);
            while (bal) {
                int sl = __ffsll(bal) - 1;
                bal &= bal - 1;
                unsigned long long mm = __shfl(msk[r], sl);
                while (mm) {
                    int cb = __ffsll(mm) - 1;
                    mm &= mm - 1;
                    int colp = (cb << 6) + sl;
                    int dst = listK[b * NN + colp];
                    atomicAdd(&A[(size_t)(b * NN + dst) * CC + lane], wgt * xv);
                    if (lane == 0) atomicAdd(&S[b * NN + dst], wgt);
                }
            }
        }
        __syncthreads();                       // mW WAR guard across slots
    }
}

// ---------------------------------------------------------------------------
// K4: out = (e*x + A) / (e + S).  A aliases d_out (in-place), float4.
// ---------------------------------------------------------------------------
__global__ __launch_bounds__(TPB) void k_finalize(const float* __restrict__ x,
                                                  const float* __restrict__ S,
                                                  float* __restrict__ out) {
    int i = blockIdx.x * TPB + threadIdx.x;
    int row = i >> 4;
    float inv = 1.0f / (E_CONST + S[row]);
    float4 xv = ((const float4*)x)[i];
    float4 av = ((float4*)out)[i];
    float4 o;
    o.x = (xv.x * E_CONST + av.x) * inv;
    o.y = (xv.y * E_CONST + av.y) * inv;
    o.z = (xv.z * E_CONST + av.z) * inv;
    o.w = (xv.w * E_CONST + av.w) * inv;
    ((float4*)out)[i] = o;
}

// ---------------------------------------------------------------------------
extern "C" void kernel_launch(void* const* d_in, const int* in_sizes, int n_in,
                              void* d_out, int out_size, void* d_ws, size_t ws_size,
                              hipStream_t stream) {
    const float* x    = (const float*)d_in[0];
    const float* keep = (const float*)d_in[2];
    float* out = (float*)d_out;

    // ws: (reserved 128KB) | S 128KB | cnts 128B | listP 128KB | listK 128KB | colM 8MB
    char* ws = (char*)d_ws;
    float* S    = (float*)(ws + (128 << 10));
    int*   cntP = (int*)(ws + (256 << 10));
    int*   cntK = cntP + 16;
    int*   listP = (int*)(ws + (256 << 10) + 128);
    int*   listK = listP + BB * NN;
    float* colMf = (float*)(ws + (1 << 20));

    k_pre<<<512, TPB, 0, stream>>>(keep, out, S, cntP, cntK, listP, listK);

    // 1-D grid, b = id&15: colM written on the XCD that k_argmax reads it on.
    k_pre2<<<BB * 64, TPB, 0, stream>>>(x, cntK, listK, colMf);

    // Persistent: 2048 blocks (2048 % 16 == 0 keeps batch/XCD pinning);
    // block walks slots {B>>4, B>>4+128} -> every resident block is live.
    k_argmax<<<2048, TPB, 0, stream>>>(x, (const float4*)colMf,
                                       cntP, cntK, listP, listK, S, out);

    k_finalize<<<(BB * NN * CC / 4) / TPB, TPB, 0, stream>>>(x, S, out);
}

// Round 8
// 120.553 us; speedup vs baseline: 1.1973x; 1.1973x over previous
//
#include <hip/hip_runtime.h>
#include <math.h>

// Problem constants (B,N,C fixed by the reference setup).
#define BB 16
#define NN 2048
#define CC 64
#define TPB 256
#define MAXT 72           // 16-token tiles per batch per side; K,P <= 1152 (+5.6 sigma)
#define IVN (MAXT * 16)
#define E_CONST 2.71828182845904523536f

typedef __attribute__((ext_vector_type(8))) short bf16x8;   // 8 bf16 = 4 VGPR
typedef __attribute__((ext_vector_type(4))) float f32x4;
#define MFMA(A_, B_, C_) __builtin_amdgcn_mfma_f32_16x16x32_bf16(A_, B_, C_, 0, 0, 0)

// round-to-nearest-even f32 -> bf16 bits (manual: no struct-bitcast issues)
__device__ __forceinline__ unsigned short rnbf16(float v) {
    unsigned u = __float_as_uint(v);
    return (unsigned short)((u + 0x7FFFu + ((u >> 16) & 1u)) >> 16);
}
__device__ __forceinline__ float bf2f(unsigned short h) {
    return __uint_as_float((unsigned)h << 16);
}

// ---------------------------------------------------------------------------
// K_pre: zero the A accumulator (d_out) everywhere; blocks 0..BB-1 also run
// ballot-based kept/pruned compaction for batch b and zero S[b,:].
// ---------------------------------------------------------------------------
__global__ __launch_bounds__(TPB) void k_pre(const float* __restrict__ keep,
                                             float* __restrict__ outz,
                                             float* __restrict__ S,
                                             int* __restrict__ cntP,
                                             int* __restrict__ cntK,
                                             int* __restrict__ listP,
                                             int* __restrict__ listK) {
    const int tid = threadIdx.x, lane = tid & 63;

    float4* o4 = (float4*)outz + (size_t)blockIdx.x * 1024;
    float4 z = {0.0f, 0.0f, 0.0f, 0.0f};
#pragma unroll
    for (int i = 0; i < 4; ++i) o4[i * TPB + tid] = z;

    const int b = blockIdx.x;
    if (b >= BB) return;

    __shared__ int cP, cK;
    if (tid == 0) { cP = 0; cK = 0; }
    __syncthreads();
    for (int i = tid; i < NN; i += TPB) S[b * NN + i] = 0.0f;
    const unsigned long long lt = (lane == 63) ? 0x7fffffffffffffffull
                                               : ((1ull << lane) - 1ull);
#pragma unroll
    for (int it = 0; it < NN / TPB; ++it) {
        int n = it * TPB + tid;
        bool kp = keep[b * NN + n] != 0.0f;
        unsigned long long mk = __ballot(kp);
        int nk = __popcll(mk);
        int bk = 0, bp = 0;
        if (lane == 0) {
            bk = atomicAdd(&cK, nk);
            bp = atomicAdd(&cP, 64 - nk);
        }
        bk = __shfl(bk, 0); bp = __shfl(bp, 0);
        int pk = __popcll(mk & lt);
        if (kp) listK[b * NN + bk + pk] = n;
        else    listP[b * NN + bp + (lane - pk)] = n;
    }
    __syncthreads();
    if (tid == 0) { cntP[b] = cP; cntK[b] = cK; }
}

// ---------------------------------------------------------------------------
// K_pack (R23, replaces k_pre2): build MFMA fragment tiles, bf16x3.
// For each 16-token tile: decompose value v = h + m + l (bf16 RNE each);
// store in A/B fragment layout for mfma_f32_16x16x32_bf16:
//   frag f = comp*2 + kfrag; lane l holds token (l&15), k = kfrag*32 +
//   (l>>4)*8 + e (e=0..7). Both operands use the IDENTICAL packing, so any
//   within-lane k-order deviation from hardware cancels in the dot product.
// cols: normalized by 1/(||x||+eps); rows: raw, ivr stored for emission.
// One wave per token: coalesced 256B load, shfl norm, LDS-staged transpose,
// coalesced 6KB tile store. Tiles t with cols >= cnt zero-padded.
// ---------------------------------------------------------------------------
__global__ __launch_bounds__(TPB) void k_pack(const float* __restrict__ x,
                                              const int* __restrict__ cnt,
                                              const int* __restrict__ list,
                                              float4* __restrict__ outF,
                                              float* __restrict__ ivrOut,
                                              int normalize) {
    const int b = blockIdx.x & 15;
    const int t = blockIdx.x >> 4;          // 0..MAXT-1
    const int lane = threadIdx.x & 63;
    const int wid  = threadIdx.x >> 6;
    const int C = cnt[b];
    __shared__ float4 stage4[384];          // 6 KB fragment tile
    unsigned short* st = (unsigned short*)stage4;
    const float* xb = x + (size_t)b * NN * CC;

    const int g  = (lane >> 3) & 3;         // k-group within 32-frag
    const int kf = lane >> 5;               // k-frag 0/1
    const int e  = lane & 7;                // element within 8
#pragma unroll
    for (int it = 0; it < 4; ++it) {
        int ci = wid * 4 + it;              // token within tile 0..15
        int cp = t * 16 + ci;               // compacted position
        float v = 0.0f;
        if (cp < C) {
            int tok = list[b * NN + cp];
            float xv = xb[(size_t)tok * CC + lane];
            float sq = xv * xv;
#pragma unroll
            for (int off = 32; off; off >>= 1) sq += __shfl_xor(sq, off, 64);
            float ivr = 1.0f / (sqrtf(sq) + 1e-6f);
            if (ivrOut && lane == 0) ivrOut[b * IVN + cp] = ivr;
            v = normalize ? xv * ivr : xv;
        }
        unsigned short hb = rnbf16(v);
        float r1 = v - bf2f(hb);
        unsigned short mb = rnbf16(r1);
        float r2 = r1 - bf2f(mb);
        unsigned short lb = rnbf16(r2);
        int lt = ci + g * 16;               // target fragment lane
        st[((0 + kf) * 64 + lt) * 8 + e] = hb;   // comp h -> frags 0,1
        st[((2 + kf) * 64 + lt) * 8 + e] = mb;   // comp m -> frags 2,3
        st[((4 + kf) * 64 + lt) * 8 + e] = lb;   // comp l -> frags 4,5
    }
    __syncthreads();
    float4* dst = outF + (size_t)(b * MAXT + t) * 384;
    for (int i = threadIdx.x; i < 384; i += TPB) dst[i] = stage4[i];
}

// ---------------------------------------------------------------------------
// K3: MFMA GEMM-argmax (R23).
// R2..R7 post-mortems: every f32-vector structure lands 65-235us because the
// VALU carries 34us of issue against a 13.7us FMA floor; occupancy was never
// the binding constraint (R7 falsified dilution). The matrix pipe moves the
// same FLOPs in ~1.7us. Swapped operands: A = kept cols (M), B = pruned rows
// (N); C/D layout (verified m89/m91) puts row = lane&15, and the lane's 4
// scores per tile at col = t*16 + (lane>>4)*4 + reg -- the per-row argmax
// reduction is IN-LANE across the whole sweep.
//  - sim = 6-term bf16x3 product sum (hh+hm+mh+hl+lh+mm, two chained acc
//    pipelines), error ~1e-7 = f32 reorder noise class -> same tie fidelity
//    as the passing f32 champion.
//  - block = one 16-row tile; wave wid sweeps tiles t = wid+4i (R6's proven
//    split-K); per-lane tie mask: 64-bit per 16-tile half (mskA/mskB, named
//    scalars -- rule #20), bit = (i&15)*4 + reg.
//  - merge via shfl(16,32) + 256B LDS table + 1 barrier; emission = R6's
//    disjoint-col ballot walk, colp = (wid+4i)*16 + (lane>>4)*4 + reg.
//  - grid 2048, b = B&15 (XCD pin), early-exit blocks proven harmless (R6).
// ---------------------------------------------------------------------------
__global__ __launch_bounds__(TPB) void k_argmax(
    const float* __restrict__ x,
    const float4* __restrict__ colA,   // [BB][MAXT] 6KB fragment tiles
    const float4* __restrict__ rowB,   // [BB][MAXT] 6KB fragment tiles
    const float* __restrict__ ivrArr,  // [BB][IVN] 1/(||row||+eps)
    const int* __restrict__ cntP, const int* __restrict__ cntK,
    const int* __restrict__ listP, const int* __restrict__ listK,
    float* __restrict__ S,             // [B,N] zeroed by k_pre
    float* __restrict__ A) {           // [B,N,C] zeroed by k_pre; = d_out

    const int b  = blockIdx.x & 15;
    const int rt = blockIdx.x >> 4;
    const int P = cntP[b], K = cntK[b];
    const int base = rt * 16;
    if (base >= P) return;

    const int lane = threadIdx.x & 63;
    const int wid  = threadIdx.x >> 6;

    // row fragments: resident for the whole sweep (24 VGPR)
    const float4* rb = rowB + (size_t)(b * MAXT + rt) * 384;
    bf16x8 B0h = __builtin_bit_cast(bf16x8, rb[0 * 64 + lane]);
    bf16x8 B1h = __builtin_bit_cast(bf16x8, rb[1 * 64 + lane]);
    bf16x8 B0m = __builtin_bit_cast(bf16x8, rb[2 * 64 + lane]);
    bf16x8 B1m = __builtin_bit_cast(bf16x8, rb[3 * 64 + lane]);
    bf16x8 B0l = __builtin_bit_cast(bf16x8, rb[4 * 64 + lane]);
    bf16x8 B1l = __builtin_bit_cast(bf16x8, rb[5 * 64 + lane]);

    float tmax = -3.0e38f;
    unsigned long long mskA = 0ull, mskB = 0ull;
    const int NT = (K + 15) >> 4;
    const float4* ca = colA + (size_t)b * MAXT * 384;
    const int cgrp = (lane >> 4) << 2;

    int i = 0;
    for (int t = wid; t < NT; t += 4, ++i) {
        const float4* af = ca + (size_t)t * 384;
        bf16x8 A0h = __builtin_bit_cast(bf16x8, af[0 * 64 + lane]);
        bf16x8 A1h = __builtin_bit_cast(bf16x8, af[1 * 64 + lane]);
        bf16x8 A0m = __builtin_bit_cast(bf16x8, af[2 * 64 + lane]);
        bf16x8 A1m = __builtin_bit_cast(bf16x8, af[3 * 64 + lane]);
        bf16x8 A0l = __builtin_bit_cast(bf16x8, af[4 * 64 + lane]);
        bf16x8 A1l = __builtin_bit_cast(bf16x8, af[5 * 64 + lane]);

        // two independent accumulation chains (small terms, then h-terms)
        f32x4 accS = {0.f, 0.f, 0.f, 0.f}, accH = {0.f, 0.f, 0.f, 0.f};
        accS = MFMA(A0m, B0m, accS); accS = MFMA(A1m, B1m, accS);   // mm
        accS = MFMA(A0h, B0l, accS); accS = MFMA(A1h, B1l, accS);   // hl
        accS = MFMA(A0l, B0h, accS); accS = MFMA(A1l, B1h, accS);   // lh
        accH = MFMA(A0h, B0m, accH); accH = MFMA(A1h, B1m, accH);   // hm
        accH = MFMA(A0m, B0h, accH); accH = MFMA(A1m, B1h, accH);   // mh
        accH = MFMA(A0h, B0h, accH); accH = MFMA(A1h, B1h, accH);   // hh

        const int cb = t * 16 + cgrp;
        const int ib = (i & 15) << 2;
#pragma unroll
        for (int j = 0; j < 4; ++j) {
            float s = accH[j] + accS[j];
            s = (cb + j < K) ? s : -3.0e38f;    // pad guard (see note)
            unsigned long long bit = 1ull << (ib | j);
            if (i < 16) {                        // wave-uniform branch
                if (s > tmax)       { tmax = s; mskA = bit; mskB = 0ull; }
                else if (s == tmax) mskA |= bit;
            } else {
                if (s > tmax)       { tmax = s; mskB = bit; mskA = 0ull; }
                else if (s == tmax) mskB |= bit;
            }
            // note: pad s == init tmax sets junk bits only while tmax is
            // still -3e38; every lane sees real cols in its first tile, so
            // junk is overwritten before it can ever be emitted (M > -3e38).
        }
    }

    // ---- merge per-row maxima: in-wave lanes r,r+16,r+32,r+48, then LDS ----
    float m = tmax;
    m = fmaxf(m, __shfl_xor(m, 16, 64));
    m = fmaxf(m, __shfl_xor(m, 32, 64));
    __shared__ float mW[16][4];
    if (lane < 16) mW[lane][wid] = m;
    __syncthreads();

    // ---- emission: each wave walks its own disjoint col subset ----
    const int nvr = min(16, P - base);
    for (int r = 0; r < nvr; ++r) {
        float M = fmaxf(fmaxf(mW[r][0], mW[r][1]), fmaxf(mW[r][2], mW[r][3]));
        unsigned long long bal = __ballot((lane & 15) == r && tmax == M);
        if (bal == 0ull) continue;              // no winners in this wave
        int src = listP[b * NN + base + r];
        float ivr = ivrArr[b * IVN + base + r];
        float wgt = expf(M * ivr);
        float xv = x[((size_t)b * NN + src) * CC + lane];
        while (bal) {
            int sl = __ffsll(bal) - 1;
            bal &= bal - 1;
            unsigned long long mA = __shfl(mskA, sl);
            unsigned long long mB = __shfl(mskB, sl);
            int cg = (sl >> 4) << 2;
            while (mA) {
                int bb = __ffsll(mA) - 1; mA &= mA - 1;
                int colp = (wid + 4 * (bb >> 2)) * 16 + cg + (bb & 3);
                int dst = listK[b * NN + colp];
                atomicAdd(&A[((size_t)b * NN + dst) * CC + lane], wgt * xv);
                if (lane == 0) atomicAdd(&S[b * NN + dst], wgt);
            }
            while (mB) {
                int bb = __ffsll(mB) - 1; mB &= mB - 1;
                int colp = (wid + 4 * (16 + (bb >> 2))) * 16 + cg + (bb & 3);
                int dst = listK[b * NN + colp];
                atomicAdd(&A[((size_t)b * NN + dst) * CC + lane], wgt * xv);
                if (lane == 0) atomicAdd(&S[b * NN + dst], wgt);
            }
        }
    }
}

// ---------------------------------------------------------------------------
// K4: out = (e*x + A) / (e + S).  A aliases d_out (in-place), float4.
// ---------------------------------------------------------------------------
__global__ __launch_bounds__(TPB) void k_finalize(const float* __restrict__ x,
                                                  const float* __restrict__ S,
                                                  float* __restrict__ out) {
    int i = blockIdx.x * TPB + threadIdx.x;
    int row = i >> 4;
    float inv = 1.0f / (E_CONST + S[row]);
    float4 xv = ((const float4*)x)[i];
    float4 av = ((float4*)out)[i];
    float4 o;
    o.x = (xv.x * E_CONST + av.x) * inv;
    o.y = (xv.y * E_CONST + av.y) * inv;
    o.z = (xv.z * E_CONST + av.z) * inv;
    o.w = (xv.w * E_CONST + av.w) * inv;
    ((float4*)out)[i] = o;
}

// ---------------------------------------------------------------------------
extern "C" void kernel_launch(void* const* d_in, const int* in_sizes, int n_in,
                              void* d_out, int out_size, void* d_ws, size_t ws_size,
                              hipStream_t stream) {
    const float* x    = (const float*)d_in[0];
    const float* keep = (const float*)d_in[2];
    float* out = (float*)d_out;

    // ws: reserved 128K | S 128K | cnts 128B | listP 128K | listK 128K |
    //     ivr 74K @768K | colA 6.75MB @1M | rowB 6.75MB @8M  (~14.8MB total)
    char* ws = (char*)d_ws;
    float* S     = (float*)(ws + (128 << 10));
    int*   cntP  = (int*)(ws + (256 << 10));
    int*   cntK  = cntP + 16;
    int*   listP = (int*)(ws + (256 << 10) + 128);
    int*   listK = listP + BB * NN;
    float* ivrArr = (float*)(ws + (768 << 10));
    float4* colA = (float4*)(ws + (1 << 20));
    float4* rowB = (float4*)(ws + (8 << 20));

    k_pre<<<512, TPB, 0, stream>>>(keep, out, S, cntP, cntK, listP, listK);

    // fragment packing: cols normalized (A-operand), rows raw + ivr (B-op).
    k_pack<<<BB * MAXT, TPB, 0, stream>>>(x, cntK, listK, colA, nullptr, 1);
    k_pack<<<BB * MAXT, TPB, 0, stream>>>(x, cntP, listP, rowB, ivrArr, 0);

    // 1-D grid: b = id & 15 (XCD pinning), rowTile = id >> 4.
    k_argmax<<<2048, TPB, 0, stream>>>(x, colA, rowB, ivrArr,
                                       cntP, cntK, listP, listK, S, out);

    k_finalize<<<(BB * NN * CC / 4) / TPB, TPB, 0, stream>>>(x, S, out);
}